// Round 1
// baseline (631.673 us; speedup 1.0000x reference)
//
#include <hip/hip_runtime.h>

// Problem constants (from reference): B=32, C=64, D=300, L=128
#define DD 300
#define LL 128
#define NBC 2048            // B*C
#define BC_PER_BLOCK 8      // 32 lanes per bc-slice (128 l / 4 per thread)
#define COS_EPS 1e-12f
#define BOUNDARY 1e-8f      // 0.0001^2

__global__ __launch_bounds__(256)
void hcmp_kernel(const float* __restrict__ x,
                 const float* __restrict__ y,
                 float* __restrict__ out) {
    const int tid = threadIdx.x;           // 0..255
    const int grp = tid >> 5;              // which bc-slice within block (0..7)
    const int t   = tid & 31;              // lane within slice: handles l = 4t..4t+3
    const int bc  = blockIdx.x * BC_PER_BLOCK + grp;   // 0..2047

    const size_t base = (size_t)bc * DD * LL + 4 * t;
    const float4* __restrict__ xp = reinterpret_cast<const float4*>(x + base);
    const float4* __restrict__ yp = reinterpret_cast<const float4*>(y + base);
    // d-step stride in float4 units: LL/4 = 32

    float dot[4] = {0.f, 0.f, 0.f, 0.f};
    float sxx[4] = {0.f, 0.f, 0.f, 0.f};
    float syy[4] = {0.f, 0.f, 0.f, 0.f};
    float ssq[4] = {0.f, 0.f, 0.f, 0.f};
    float sl1[4] = {0.f, 0.f, 0.f, 0.f};

    #pragma unroll 4
    for (int d = 0; d < DD; ++d) {
        float4 a = xp[(size_t)d * (LL / 4)];
        float4 b = yp[(size_t)d * (LL / 4)];

        float ax[4] = {a.x, a.y, a.z, a.w};
        float bx[4] = {b.x, b.y, b.z, b.w};
        #pragma unroll
        for (int k = 0; k < 4; ++k) {
            dot[k] = fmaf(ax[k], bx[k], dot[k]);
            sxx[k] = fmaf(ax[k], ax[k], sxx[k]);
            syy[k] = fmaf(bx[k], bx[k], syy[k]);
            float df = ax[k] - bx[k];
            ssq[k] = fmaf(df, df, ssq[k]);
            sl1[k] += fabsf(df);
        }
    }

    const size_t row0 = (size_t)bc * LL + 4 * t;
    #pragma unroll
    for (int k = 0; k < 4; ++k) {
        float nx = fmaxf(sqrtf(sxx[k]), COS_EPS);
        float ny = fmaxf(sqrtf(syy[k]), COS_EPS);
        float c  = dot[k] / (nx * ny);
        float sq = ssq[k];
        if (sq < BOUNDARY) sq += BOUNDARY;   // revise_zero_data
        float l2 = sqrtf(sq);
        size_t o = (row0 + k) * 3;
        out[o + 0] = c;
        out[o + 1] = l2;
        out[o + 2] = sl1[k];
    }
}

extern "C" void kernel_launch(void* const* d_in, const int* in_sizes, int n_in,
                              void* d_out, int out_size, void* d_ws, size_t ws_size,
                              hipStream_t stream) {
    const float* x = (const float*)d_in[0];
    const float* y = (const float*)d_in[1];
    float* out = (float*)d_out;

    dim3 grid(NBC / BC_PER_BLOCK);   // 256 blocks
    dim3 block(256);
    hcmp_kernel<<<grid, block, 0, stream>>>(x, y, out);
}